// Round 1
// baseline (1383.179 us; speedup 1.0000x reference)
//
#include <hip/hip_runtime.h>
#include <math.h>

#define N_PIX 4096
#define CDIM 256
#define DINNER 512
#define HEADS 8
#define DHEAD 64

typedef float vf4 __attribute__((ext_vector_type(4)));

constexpr float SCALE = 0.125f;   // 64^-0.5

// ---------------------------------------------------------------------------
// Kernel 1: per-pixel channel L2 norm -> rnorm = sqrt(256)/max(||x||,1e-12)
// block: 256 threads = 64 pixels x 4 channel-quarters
// ---------------------------------------------------------------------------
__global__ __launch_bounds__(256) void rnorm_kernel(const float* __restrict__ fmap,
                                                    float* __restrict__ rnorm) {
    __shared__ float red[4][64];
    const int t = threadIdx.x;
    const int pl = t & 63;        // pixel within block
    const int part = t >> 6;      // channel quarter
    const int pix0 = blockIdx.x * 64;          // 128 blocks * 64 = 8192 pixels
    const int gp = pix0 + pl;                  // global pixel incl. batch
    const int b = gp >> 12, p = gp & 4095;
    const float* f = fmap + ((size_t)b * CDIM + part * 64) * N_PIX + p;
    float s = 0.f;
    #pragma unroll 8
    for (int c = 0; c < 64; ++c) { float x = f[(size_t)c * N_PIX]; s = fmaf(x, x, s); }
    red[part][pl] = s;
    __syncthreads();
    if (t < 64) {
        float tot = red[0][t] + red[1][t] + red[2][t] + red[3][t];
        rnorm[pix0 + t] = 16.0f / fmaxf(sqrtf(tot), 1e-12f);
    }
}

// ---------------------------------------------------------------------------
// Kernel 2: projection GEMM.  out[o][p] = rnorm[p] * sum_c (W[o][c]*gamma[c]) * fmap[b][c][p]
// Q rows o<512 from Wq, V rows from Wv.  Tile 64x64, K-step 16, 256 threads, 4x4/thread.
// ---------------------------------------------------------------------------
__global__ __launch_bounds__(256) void proj_kernel(
    const float* __restrict__ fmap, const float* __restrict__ gamma,
    const float* __restrict__ Wq, const float* __restrict__ Wv,
    const float* __restrict__ rnorm, float* __restrict__ Qb, float* __restrict__ Vb) {
    const int pt = blockIdx.x, mt = blockIdx.y, b = blockIdx.z;
    const int p0 = pt * 64, m0 = mt * 64;
    const float* W; float* Ob; int or0;
    if (m0 < DINNER) { W = Wq; Ob = Qb; or0 = m0; }
    else             { W = Wv; Ob = Vb; or0 = m0 - DINNER; }

    __shared__ float As[16][68];   // [kk][m]
    __shared__ float Bs[16][68];   // [kk][p]
    const int t = threadIdx.x, tm = t >> 4, tn = t & 15;
    float acc[4][4] = {};

    for (int kt = 0; kt < CDIM; kt += 16) {
        __syncthreads();
        for (int e = t; e < 1024; e += 256) {
            int m = e >> 4, kk = e & 15;
            As[kk][m] = W[(size_t)(or0 + m) * CDIM + kt + kk] * gamma[kt + kk];
        }
        for (int e = t; e < 1024; e += 256) {
            int kk = e >> 6, pp = e & 63;
            Bs[kk][pp] = fmap[((size_t)b * CDIM + kt + kk) * N_PIX + p0 + pp];
        }
        __syncthreads();
        #pragma unroll
        for (int kk = 0; kk < 16; ++kk) {
            vf4 a = *(const vf4*)&As[kk][4 * tm];
            vf4 bb = *(const vf4*)&Bs[kk][4 * tn];
            #pragma unroll
            for (int r = 0; r < 4; ++r)
                #pragma unroll
                for (int c = 0; c < 4; ++c)
                    acc[r][c] = fmaf(a[r], bb[c], acc[r][c]);
        }
    }
    #pragma unroll
    for (int r = 0; r < 4; ++r) {
        vf4 o4;
        #pragma unroll
        for (int c = 0; c < 4; ++c) {
            int p = p0 + 4 * tn + c;
            o4[c] = acc[r][c] * rnorm[b * N_PIX + p];
        }
        *(vf4*)&Ob[((size_t)b * DINNER + or0 + 4 * tm + r) * N_PIX + p0 + 4 * tn] = o4;
    }
}

// ---------------------------------------------------------------------------
// Kernel 3: flash attention, neg. squared L2 scores, k = q, null kv at j=0.
// Layouts: Q,V,O are [b][o=h*64+d][p] (pixel contiguous).
// Block: 64 q-rows, 256 threads. sim row-constant q^2 term dropped (softmax-invariant).
// ---------------------------------------------------------------------------
__global__ __launch_bounds__(256) void attn_kernel(
    const float* __restrict__ Q, const float* __restrict__ V,
    const float* __restrict__ nullkv, float* __restrict__ O) {
    const int it = blockIdx.x;           // 64 i-tiles
    const int bh = blockIdx.y;           // 16
    const int b = bh >> 3, h = bh & 7;
    const float* qb = Q + (size_t)(b * DINNER + h * DHEAD) * N_PIX;
    const float* vb = V + (size_t)(b * DINNER + h * DHEAD) * N_PIX;
    const int i0 = it * 64;

    __shared__ float q_lds[64][68];      // [d][ii]
    __shared__ float k_lds[64][68];      // [d][jj]
    __shared__ float v_lds[64][68];      // [jj][dd]  (transposed for PV float4 reads)
    __shared__ float s_lds[64][68];      // [ii][jj]  dot, then p
    __shared__ float ksq[64];
    __shared__ float row_m[64], row_l[64], fac[64];
    __shared__ float red[4][64];
    __shared__ float nk_s[64], nv_s[64];

    const int t = threadIdx.x;
    const int ti = t >> 4, td = t & 15;
    const int r64 = t & 63, quad = t >> 6;

    for (int e = t; e < 4096; e += 256) {
        int d = e >> 6, ii = e & 63;
        q_lds[d][ii] = qb[(size_t)d * N_PIX + i0 + ii];
    }
    if (t < 64) {
        nk_s[t] = nullkv[h * DHEAD + t];
        nv_s[t] = nullkv[DINNER + h * DHEAD + t];
    }
    __syncthreads();

    // init running stats with null kv (weight exp(0)=1)
    if (t < 64) {
        float nksq = 0.f, dot = 0.f;
        for (int d = 0; d < 64; ++d) {
            float nk = nk_s[d];
            nksq = fmaf(nk, nk, nksq);
            dot  = fmaf(q_lds[d][t], nk, dot);
        }
        row_m[t] = fmaf(2.f, dot, -nksq) * SCALE;
        row_l[t] = 1.f;
    }
    float acc[4][4];
    #pragma unroll
    for (int r = 0; r < 4; ++r)
        #pragma unroll
        for (int c = 0; c < 4; ++c) acc[r][c] = nv_s[4 * td + c];

    for (int jt = 0; jt < 64; ++jt) {
        __syncthreads();                  // prev PV done before overwrite
        const int j0 = jt * 64;
        for (int e = t; e < 4096; e += 256) {
            int d = e >> 6, jj = e & 63;
            float kvl = qb[(size_t)d * N_PIX + j0 + jj];
            float vvl = vb[(size_t)d * N_PIX + j0 + jj];
            k_lds[d][jj] = kvl;
            v_lds[jj][d] = vvl;
        }
        __syncthreads();

        if (t < 64) {                     // ksq by wave 0, overlapped with S-phase
            float s = 0.f;
            for (int d = 0; d < 64; ++d) { float x = k_lds[d][t]; s = fmaf(x, x, s); }
            ksq[t] = s;
        }
        // S-phase: dot(q_i, k_j), 4x4 per thread
        float s4[4][4] = {};
        #pragma unroll 8
        for (int d = 0; d < 64; ++d) {
            vf4 qa = *(const vf4*)&q_lds[d][4 * ti];
            vf4 kb = *(const vf4*)&k_lds[d][4 * td];
            #pragma unroll
            for (int r = 0; r < 4; ++r)
                #pragma unroll
                for (int c = 0; c < 4; ++c)
                    s4[r][c] = fmaf(qa[r], kb[c], s4[r][c]);
        }
        #pragma unroll
        for (int r = 0; r < 4; ++r)
            *(vf4*)&s_lds[4 * ti + r][4 * td] =
                vf4{s4[r][0], s4[r][1], s4[r][2], s4[r][3]};
        __syncthreads();

        // wave-parallel online softmax: row r64, j-quarter quad
        float mx = -3.4e38f;
        #pragma unroll 4
        for (int jj = 0; jj < 16; ++jj) {
            int j = quad * 16 + jj;
            float sv = fmaf(2.f, s_lds[r64][j], -ksq[j]) * SCALE;
            mx = fmaxf(mx, sv);
        }
        red[quad][r64] = mx;
        __syncthreads();
        if (t < 64) {
            float mold = row_m[t];
            float mnew = fmaxf(fmaxf(fmaxf(red[0][t], red[1][t]),
                                     fmaxf(red[2][t], red[3][t])), mold);
            fac[t] = __expf(mold - mnew);
            row_m[t] = mnew;
        }
        __syncthreads();
        float mnew = row_m[r64], ps = 0.f;
        #pragma unroll 4
        for (int jj = 0; jj < 16; ++jj) {
            int j = quad * 16 + jj;
            float sv = fmaf(2.f, s_lds[r64][j], -ksq[j]) * SCALE;
            float p = __expf(sv - mnew);
            s_lds[r64][j] = p;
            ps += p;
        }
        red[quad][r64] = ps;
        __syncthreads();
        if (t < 64)
            row_l[t] = row_l[t] * fac[t] + red[0][t] + red[1][t] + red[2][t] + red[3][t];
        __syncthreads();

        // PV: acc[i][dd] = acc*fac + sum_j p[i][j] * v[j][dd]
        #pragma unroll
        for (int r = 0; r < 4; ++r) {
            float fr = fac[4 * ti + r];
            #pragma unroll
            for (int c = 0; c < 4; ++c) acc[r][c] *= fr;
        }
        #pragma unroll 2
        for (int jc = 0; jc < 64; jc += 4) {
            vf4 p4[4], vv[4];
            #pragma unroll
            for (int r = 0; r < 4; ++r) p4[r] = *(const vf4*)&s_lds[4 * ti + r][jc];
            #pragma unroll
            for (int e = 0; e < 4; ++e) vv[e] = *(const vf4*)&v_lds[jc + e][4 * td];
            #pragma unroll
            for (int r = 0; r < 4; ++r)
                #pragma unroll
                for (int e = 0; e < 4; ++e)
                    #pragma unroll
                    for (int c = 0; c < 4; ++c)
                        acc[r][c] = fmaf(p4[r][e], vv[e][c], acc[r][c]);
        }
    }

    float linv[4];
    #pragma unroll
    for (int r = 0; r < 4; ++r) linv[r] = 1.f / row_l[4 * ti + r];
    float* ob = O + (size_t)(b * DINNER + h * DHEAD) * N_PIX;
    #pragma unroll
    for (int c = 0; c < 4; ++c) {
        vf4 o4;
        #pragma unroll
        for (int r = 0; r < 4; ++r) o4[r] = acc[r][c] * linv[r];
        *(vf4*)&ob[(size_t)(4 * td + c) * N_PIX + i0 + 4 * ti] = o4;
    }
}

// ---------------------------------------------------------------------------
// Kernel 4: output GEMM  out[o=256][p] = sum_c Wout[o][c] * AO[b][c][p], c over 512
// ---------------------------------------------------------------------------
__global__ __launch_bounds__(256) void outproj_kernel(
    const float* __restrict__ AO, const float* __restrict__ Wout,
    float* __restrict__ out) {
    const int pt = blockIdx.x, mt = blockIdx.y, b = blockIdx.z;
    const int p0 = pt * 64, m0 = mt * 64;
    __shared__ float As[16][68];
    __shared__ float Bs[16][68];
    const int t = threadIdx.x, tm = t >> 4, tn = t & 15;
    float acc[4][4] = {};
    for (int kt = 0; kt < DINNER; kt += 16) {
        __syncthreads();
        for (int e = t; e < 1024; e += 256) {
            int m = e >> 4, kk = e & 15;
            As[kk][m] = Wout[(size_t)(m0 + m) * DINNER + kt + kk];
        }
        for (int e = t; e < 1024; e += 256) {
            int kk = e >> 6, pp = e & 63;
            Bs[kk][pp] = AO[((size_t)b * DINNER + kt + kk) * N_PIX + p0 + pp];
        }
        __syncthreads();
        #pragma unroll
        for (int kk = 0; kk < 16; ++kk) {
            vf4 a = *(const vf4*)&As[kk][4 * tm];
            vf4 bb = *(const vf4*)&Bs[kk][4 * tn];
            #pragma unroll
            for (int r = 0; r < 4; ++r)
                #pragma unroll
                for (int c = 0; c < 4; ++c)
                    acc[r][c] = fmaf(a[r], bb[c], acc[r][c]);
        }
    }
    #pragma unroll
    for (int r = 0; r < 4; ++r) {
        vf4 o4 = {acc[r][0], acc[r][1], acc[r][2], acc[r][3]};
        *(vf4*)&out[((size_t)b * CDIM + m0 + 4 * tm + r) * N_PIX + p0 + 4 * tn] = o4;
    }
}

// ---------------------------------------------------------------------------
extern "C" void kernel_launch(void* const* d_in, const int* in_sizes, int n_in,
                              void* d_out, int out_size, void* d_ws, size_t ws_size,
                              hipStream_t stream) {
    const float* fmap   = (const float*)d_in[0];
    const float* gamma  = (const float*)d_in[1];
    const float* Wq     = (const float*)d_in[2];
    const float* Wv     = (const float*)d_in[3];
    const float* Wout   = (const float*)d_in[4];
    const float* nullkv = (const float*)d_in[5];
    float* out = (float*)d_out;

    float* ws = (float*)d_ws;
    float* rnorm = ws;                                  // 8192
    float* Qb    = ws + 8192;                           // 2*512*4096
    float* Vb    = Qb + (size_t)2 * DINNER * N_PIX;     // 2*512*4096
    float* AO    = Vb + (size_t)2 * DINNER * N_PIX;     // 2*512*4096

    rnorm_kernel<<<128, 256, 0, stream>>>(fmap, rnorm);
    proj_kernel<<<dim3(64, 16, 2), 256, 0, stream>>>(fmap, gamma, Wq, Wv, rnorm, Qb, Vb);
    attn_kernel<<<dim3(64, 16), 256, 0, stream>>>(Qb, Vb, nullkv, AO);
    outproj_kernel<<<dim3(64, 4, 2), 256, 0, stream>>>(AO, Wout, out);
}

// Round 3
// 495.250 us; speedup vs baseline: 2.7929x; 2.7929x over previous
//
#include <hip/hip_runtime.h>
#include <math.h>
#include <stdint.h>

#define N_PIX 4096
#define CDIM 256
#define DINNER 512
#define HEADS 8
#define DHEAD 64

typedef float vf4 __attribute__((ext_vector_type(4)));
typedef float f32x4 __attribute__((ext_vector_type(4)));
typedef _Float16 half8 __attribute__((ext_vector_type(8)));
typedef _Float16 half4v __attribute__((ext_vector_type(4)));

constexpr float SCALE = 0.125f;   // 64^-0.5

// ---------------------------------------------------------------------------
// Kernel 1: per-pixel channel L2 norm -> rnorm = sqrt(256)/max(||x||,1e-12)
// ---------------------------------------------------------------------------
__global__ __launch_bounds__(256) void rnorm_kernel(const float* __restrict__ fmap,
                                                    float* __restrict__ rnorm) {
    __shared__ float red[4][64];
    const int t = threadIdx.x;
    const int pl = t & 63;
    const int part = t >> 6;
    const int pix0 = blockIdx.x * 64;
    const int gp = pix0 + pl;
    const int b = gp >> 12, p = gp & 4095;
    const float* f = fmap + ((size_t)b * CDIM + part * 64) * N_PIX + p;
    float s = 0.f;
    #pragma unroll 8
    for (int c = 0; c < 64; ++c) { float x = f[(size_t)c * N_PIX]; s = fmaf(x, x, s); }
    red[part][pl] = s;
    __syncthreads();
    if (t < 64) {
        float tot = red[0][t] + red[1][t] + red[2][t] + red[3][t];
        rnorm[pix0 + t] = 16.0f / fmaxf(sqrtf(tot), 1e-12f);
    }
}

// ---------------------------------------------------------------------------
// Kernel 2: projection GEMM -> fp16 Qh [bh][p][64], fp16 Vh [bh][64][p],
// cksq [bh][p] = 0.125*sum_d qh^2 (from ROUNDED fp16 q, so diag max is exact).
// ---------------------------------------------------------------------------
__global__ __launch_bounds__(256) void proj_kernel(
    const float* __restrict__ fmap, const float* __restrict__ gamma,
    const float* __restrict__ Wq, const float* __restrict__ Wv,
    const float* __restrict__ rnorm,
    _Float16* __restrict__ Qh, _Float16* __restrict__ Vh,
    float* __restrict__ cksq) {
    const int pt = blockIdx.x, mt = blockIdx.y, b = blockIdx.z;
    const int p0 = pt * 64, m0 = mt * 64;
    const bool isQ = (m0 < DINNER);
    const float* W = isQ ? Wq : Wv;
    const int or0 = isQ ? m0 : m0 - DINNER;
    const int h = or0 >> 6;           // head
    const int bh = b * 8 + h;

    __shared__ float As[16][68];
    __shared__ float Bs[16][68];
    const int t = threadIdx.x, tm = t >> 4, tn = t & 15;
    float acc[4][4] = {};

    for (int kt = 0; kt < CDIM; kt += 16) {
        __syncthreads();
        for (int e = t; e < 1024; e += 256) {
            int m = e >> 4, kk = e & 15;
            As[kk][m] = W[(size_t)(or0 + m) * CDIM + kt + kk] * gamma[kt + kk];
        }
        for (int e = t; e < 1024; e += 256) {
            int kk = e >> 6, pp = e & 63;
            Bs[kk][pp] = fmap[((size_t)b * CDIM + kt + kk) * N_PIX + p0 + pp];
        }
        __syncthreads();
        #pragma unroll
        for (int kk = 0; kk < 16; ++kk) {
            vf4 a = *(const vf4*)&As[kk][4 * tm];
            vf4 bb = *(const vf4*)&Bs[kk][4 * tn];
            #pragma unroll
            for (int r = 0; r < 4; ++r)
                #pragma unroll
                for (int c = 0; c < 4; ++c)
                    acc[r][c] = fmaf(a[r], bb[c], acc[r][c]);
        }
    }

    // apply rnorm, round to fp16
    _Float16 hq[4][4];
    float part[4] = {0.f, 0.f, 0.f, 0.f};
    #pragma unroll
    for (int c = 0; c < 4; ++c) {
        float rn = rnorm[b * N_PIX + p0 + 4 * tn + c];
        #pragma unroll
        for (int r = 0; r < 4; ++r) {
            _Float16 hv = (_Float16)(acc[r][c] * rn);
            hq[r][c] = hv;
            float qrf = (float)hv;
            part[c] = fmaf(qrf, qrf, part[c]);
        }
    }

    if (isQ) {
        // Qh[bh][p][d]
        #pragma unroll
        for (int c = 0; c < 4; ++c) {
            half4v hv = {hq[0][c], hq[1][c], hq[2][c], hq[3][c]};
            *(half4v*)(Qh + ((size_t)bh * N_PIX + p0 + 4 * tn + c) * 64 + 4 * tm) = hv;
        }
        // reduce per-pixel ksq over the 16 tm groups via LDS (reuse Bs)
        __syncthreads();
        *(vf4*)&Bs[tm][4 * tn] = vf4{part[0], part[1], part[2], part[3]};
        __syncthreads();
        if (t < 64) {
            float s = 0.f;
            #pragma unroll
            for (int r = 0; r < 16; ++r) s += Bs[r][t];
            cksq[(size_t)bh * N_PIX + p0 + t] = 0.125f * s;
        }
    } else {
        // Vh[bh][d][p]
        #pragma unroll
        for (int r = 0; r < 4; ++r) {
            half4v hv = {hq[r][0], hq[r][1], hq[r][2], hq[r][3]};
            *(half4v*)(Vh + ((size_t)bh * 64 + 4 * tm + r) * N_PIX + p0 + 4 * tn) = hv;
        }
    }
}

// ---------------------------------------------------------------------------
// Kernel 3: fp16 MFMA flash attention via SWAPPED QK^T (S^T = mfma(K, Q)).
// k = q; null kv handled analytically; m_i = max(0.125*qsq_i, nullsim_i) is
// known upfront (diagonal is the row max) -> no online rescale, no barriers.
// Lane l holds P[i = l&15][j = jt*16 + (l>>4)*4 + r] after the S^T mfma,
// which is exactly the PV B-operand fragment (k-map mu(g,e) shared with the
// V A-operand) -> no LDS transpose needed at all.
// Block = 4 waves x 32 q-rows (2 strips of 16). KV tile = 64.
// ---------------------------------------------------------------------------
__global__ __launch_bounds__(256, 2) void attn_kernel(
    const _Float16* __restrict__ Qh,   // [bh][p][64]
    const _Float16* __restrict__ Vh,   // [bh][64][p]
    const float* __restrict__ cksq,    // [bh][p] = 0.125*ksq
    const float* __restrict__ nullkv,  // [2][8][64] fp32
    float* __restrict__ AO)            // [b][512][p]
{
    const int n = blockIdx.x;
    const int slot = n >> 3;
    const int bh = (n & 7) * 2 + (slot >> 5);   // XCD swizzle: 2 bh per XCD
    const int it = slot & 31;
    const int h = bh & 7;

    __shared__ float ksq_lds[4096];

    const int t = threadIdx.x;
    const int w = t >> 6;
    const int lane = t & 63;
    const int col = lane & 15;
    const int g = lane >> 4;

    const float* ck = cksq + (size_t)bh * N_PIX;
    for (int e = t; e < 4096; e += 256) ksq_lds[e] = ck[e];
    __syncthreads();

    const int i0 = it * 128 + w * 32;
    const _Float16* qbase = Qh + (size_t)bh * N_PIX * 64;
    const _Float16* vbase = Vh + (size_t)bh * 64 * N_PIX;

    // Q fragments (B-operand of S^T mfma): row = l&15 (q-row), k-map d = dk*32+g*8+e
    half8 qf[2][2];
    #pragma unroll
    for (int s = 0; s < 2; ++s)
        #pragma unroll
        for (int dk = 0; dk < 2; ++dk)
            qf[s][dk] = *(const half8*)(qbase + ((size_t)(i0 + s * 16 + col)) * 64 + dk * 32 + g * 8);

    // null kv: per-lane nd for q-row = l&15 after g-group reduction
    float nkv[2][8];
    #pragma unroll
    for (int dk = 0; dk < 2; ++dk) {
        const float* np = nullkv + h * 64 + dk * 32 + g * 8;
        vf4 a = *(const vf4*)np;
        vf4 b2 = *(const vf4*)(np + 4);
        nkv[dk][0] = a[0]; nkv[dk][1] = a[1]; nkv[dk][2] = a[2]; nkv[dk][3] = a[3];
        nkv[dk][4] = b2[0]; nkv[dk][5] = b2[1]; nkv[dk][6] = b2[2]; nkv[dk][7] = b2[3];
    }
    float nd0 = 0.f, nd1 = 0.f, nkk = 0.f;
    #pragma unroll
    for (int dk = 0; dk < 2; ++dk)
        #pragma unroll
        for (int e = 0; e < 8; ++e) {
            float nkval = nkv[dk][e];
            nkk = fmaf(nkval, nkval, nkk);
            nd0 = fmaf((float)qf[0][dk][e], nkval, nd0);
            nd1 = fmaf((float)qf[1][dk][e], nkval, nd1);
        }
    nd0 += __shfl_xor(nd0, 16); nd0 += __shfl_xor(nd0, 32);
    nd1 += __shfl_xor(nd1, 16); nd1 += __shfl_xor(nd1, 32);
    nkk += __shfl_xor(nkk, 16); nkk += __shfl_xor(nkk, 32);

    // null V values at d = dt*16 + 4g + r (matches O^T D-layout row = g*4+r)
    vf4 nv4[4];
    #pragma unroll
    for (int dt = 0; dt < 4; ++dt)
        nv4[dt] = *(const vf4*)(nullkv + DINNER + h * 64 + dt * 16 + 4 * g);

    float m_[2], l_[2];
    f32x4 oaccT[2][4];
    #pragma unroll
    for (int s = 0; s < 2; ++s) {
        float ndv = (s == 0) ? nd0 : nd1;
        float nsim = fmaf(0.25f, ndv, -0.125f * nkk);
        float ci = ksq_lds[i0 + s * 16 + col];
        float m = fmaxf(ci, nsim);
        m_[s] = m;
        float wn = __expf(nsim - m);
        l_[s] = wn * 0.25f;               // null l split across the 4 g-lanes
        #pragma unroll
        for (int dt = 0; dt < 4; ++dt)
            #pragma unroll
            for (int r = 0; r < 4; ++r)
                oaccT[s][dt][r] = wn * nv4[dt][r];
    }

    for (int jt64 = 0; jt64 < 64; ++jt64) {
        const int j0 = jt64 * 64;
        // K fragments (A-operand, k = q): row = l&15 (k-row), same k-map as Q
        half8 kf[4][2];
        #pragma unroll
        for (int jt = 0; jt < 4; ++jt)
            #pragma unroll
            for (int dk = 0; dk < 2; ++dk)
                kf[jt][dk] = *(const half8*)(qbase + (size_t)(j0 + jt * 16 + col) * 64 + dk * 32 + g * 8);
        // V fragments (A-operand of PV): row = l&15 = d-offset,
        // k-map j = kv*32 + (e>>2)*16 + g*4 + (e&3)
        half8 vfr[2][4];
        #pragma unroll
        for (int kv = 0; kv < 2; ++kv)
            #pragma unroll
            for (int dt = 0; dt < 4; ++dt) {
                const _Float16* vptr = vbase + (size_t)(dt * 16 + col) * N_PIX + j0 + kv * 32 + g * 4;
                half4v vA = *(const half4v*)vptr;
                half4v vB = *(const half4v*)(vptr + 16);
                vfr[kv][dt] = __builtin_shufflevector(vA, vB, 0, 1, 2, 3, 4, 5, 6, 7);
            }
        // ksq for this lane's j values: j = jt*16 + 4g + r
        vf4 cj[4];
        #pragma unroll
        for (int jt = 0; jt < 4; ++jt)
            cj[jt] = *(const vf4*)&ksq_lds[j0 + jt * 16 + 4 * g];

        #pragma unroll
        for (int s = 0; s < 2; ++s) {
            // S^T: D[row = k-row g*4+r][col = q-row l&15]
            f32x4 sfT[4];
            #pragma unroll
            for (int jt = 0; jt < 4; ++jt) {
                sfT[jt] = f32x4{0.f, 0.f, 0.f, 0.f};
                #pragma unroll
                for (int dk = 0; dk < 2; ++dk)
                    sfT[jt] = __builtin_amdgcn_mfma_f32_16x16x32_f16(kf[jt][dk], qf[s][dk], sfT[jt], 0, 0, 0);
            }
            // softmax: m fixed (diag max), i = l&15 -> per-lane scalar
            const float m = m_[s];
            float lacc = l_[s];
            float pv[4][4];
            #pragma unroll
            for (int jt = 0; jt < 4; ++jt)
                #pragma unroll
                for (int r = 0; r < 4; ++r) {
                    float p = __expf(fmaf(0.25f, sfT[jt][r], -cj[jt][r] - m));
                    pv[jt][r] = p;
                    lacc += p;
                }
            l_[s] = lacc;
            half8 pf0 = {(_Float16)pv[0][0], (_Float16)pv[0][1], (_Float16)pv[0][2], (_Float16)pv[0][3],
                         (_Float16)pv[1][0], (_Float16)pv[1][1], (_Float16)pv[1][2], (_Float16)pv[1][3]};
            half8 pf1 = {(_Float16)pv[2][0], (_Float16)pv[2][1], (_Float16)pv[2][2], (_Float16)pv[2][3],
                         (_Float16)pv[3][0], (_Float16)pv[3][1], (_Float16)pv[3][2], (_Float16)pv[3][3]};
            // O^T[d][i] += sum_j V[d][j] * P[i][j]
            #pragma unroll
            for (int dt = 0; dt < 4; ++dt) {
                oaccT[s][dt] = __builtin_amdgcn_mfma_f32_16x16x32_f16(vfr[0][dt], pf0, oaccT[s][dt], 0, 0, 0);
                oaccT[s][dt] = __builtin_amdgcn_mfma_f32_16x16x32_f16(vfr[1][dt], pf1, oaccT[s][dt], 0, 0, 0);
            }
        }
    }

    // epilogue: reduce l over the 4 g-lanes, normalize, store
    float* aob = AO + ((size_t)(bh >> 3) * DINNER + h * 64) * N_PIX;
    #pragma unroll
    for (int s = 0; s < 2; ++s) {
        float l = l_[s];
        l += __shfl_xor(l, 16); l += __shfl_xor(l, 32);
        float linv = 1.f / l;
        const int p = i0 + s * 16 + col;
        #pragma unroll
        for (int dt = 0; dt < 4; ++dt)
            #pragma unroll
            for (int r = 0; r < 4; ++r)
                aob[(size_t)(dt * 16 + 4 * g + r) * N_PIX + p] = oaccT[s][dt][r] * linv;
    }
}

// ---------------------------------------------------------------------------
// Kernel 4: output GEMM  out[o=256][p] = sum_c Wout[o][c] * AO[b][c][p]
// ---------------------------------------------------------------------------
__global__ __launch_bounds__(256) void outproj_kernel(
    const float* __restrict__ AO, const float* __restrict__ Wout,
    float* __restrict__ out) {
    const int pt = blockIdx.x, mt = blockIdx.y, b = blockIdx.z;
    const int p0 = pt * 64, m0 = mt * 64;
    __shared__ float As[16][68];
    __shared__ float Bs[16][68];
    const int t = threadIdx.x, tm = t >> 4, tn = t & 15;
    float acc[4][4] = {};
    for (int kt = 0; kt < DINNER; kt += 16) {
        __syncthreads();
        for (int e = t; e < 1024; e += 256) {
            int m = e >> 4, kk = e & 15;
            As[kk][m] = Wout[(size_t)(m0 + m) * DINNER + kt + kk];
        }
        for (int e = t; e < 1024; e += 256) {
            int kk = e >> 6, pp = e & 63;
            Bs[kk][pp] = AO[((size_t)b * DINNER + kt + kk) * N_PIX + p0 + pp];
        }
        __syncthreads();
        #pragma unroll
        for (int kk = 0; kk < 16; ++kk) {
            vf4 a = *(const vf4*)&As[kk][4 * tm];
            vf4 bb = *(const vf4*)&Bs[kk][4 * tn];
            #pragma unroll
            for (int r = 0; r < 4; ++r)
                #pragma unroll
                for (int c = 0; c < 4; ++c)
                    acc[r][c] = fmaf(a[r], bb[c], acc[r][c]);
        }
    }
    #pragma unroll
    for (int r = 0; r < 4; ++r) {
        vf4 o4 = {acc[r][0], acc[r][1], acc[r][2], acc[r][3]};
        *(vf4*)&out[((size_t)b * CDIM + m0 + 4 * tm + r) * N_PIX + p0 + 4 * tn] = o4;
    }
}

// ---------------------------------------------------------------------------
extern "C" void kernel_launch(void* const* d_in, const int* in_sizes, int n_in,
                              void* d_out, int out_size, void* d_ws, size_t ws_size,
                              hipStream_t stream) {
    const float* fmap   = (const float*)d_in[0];
    const float* gamma  = (const float*)d_in[1];
    const float* Wq     = (const float*)d_in[2];
    const float* Wv     = (const float*)d_in[3];
    const float* Wout   = (const float*)d_in[4];
    const float* nullkv = (const float*)d_in[5];
    float* out = (float*)d_out;

    char* wsb = (char*)d_ws;
    _Float16* Qh  = (_Float16*)wsb;                          // 8 MB
    _Float16* Vh  = (_Float16*)(wsb + (8u << 20));           // 8 MB
    float*    AO  = (float*)(wsb + (16u << 20));             // 16 MB
    float*    cksq = (float*)(wsb + (32u << 20));            // 256 KB
    float*    rnorm = (float*)(wsb + (33u << 20));           // 32 KB

    rnorm_kernel<<<128, 256, 0, stream>>>(fmap, rnorm);
    proj_kernel<<<dim3(64, 16, 2), 256, 0, stream>>>(fmap, gamma, Wq, Wv, rnorm, Qh, Vh, cksq);
    attn_kernel<<<512, 256, 0, stream>>>(Qh, Vh, cksq, nullkv, AO);
    outproj_kernel<<<dim3(64, 4, 2), 256, 0, stream>>>(AO, Wout, out);
}